// Round 15
// baseline (334.954 us; speedup 1.0000x reference)
//
#include <hip/hip_runtime.h>

#define NN 100000
#define NE 1600000
#define DD 128            // IN_DIM == HID == 128
#define OUT_HALF 6400000  // NN * 64
#define CAP 64            // slots per node (max degree on this fixed graph ~42)

// ---- binned-build parameters ----
#define NB 256            // coarse destination buckets (== k_bin block size)
#define NPB 391           // nodes per bucket (256*391 = 100096 >= NN)
#define BCAP 8192         // record capacity per bucket (E[n]=6250, +24 sigma)
#define BSTRIDE 64        // ints between bucket counters (256B apart)
#define CHUNK 2048        // edges per k_bin block (782 blocks = 3/CU)
#define CPT 8             // CHUNK / 256

// ---- MFMA GEMM tile: 64 nodes/block, 4 waves, wave = 16 nodes x 128 cols ----
// LDS tile is exactly 64x128 fp32 = 32 KB with an XOR swizzle on the float4
// index (f4 ^ (row&7)) -> conflict-free; b128 reads 8 lanes/quad uniform.
#define GNM 64            // nodes per block

typedef unsigned int uint_t;
typedef float v4f __attribute__((ext_vector_type(4)));
typedef short v8s __attribute__((ext_vector_type(8)));

// round-to-nearest-even fp32 -> bf16 (as ushort)
__device__ __forceinline__ unsigned short f2bf(float f) {
    uint_t u = __float_as_uint(f);
    u = (u + 0x7fffu + ((u >> 16) & 1u)) >> 16;
    return (unsigned short)u;
}
__device__ __forceinline__ float bf2f(unsigned short h) {
    return __uint_as_float(((uint_t)h) << 16);
}
__device__ __forceinline__ float bf_lo(uint_t u) { return __uint_as_float(u << 16); }
__device__ __forceinline__ float bf_hi(uint_t u) { return __uint_as_float(u & 0xffff0000u); }

#define EW_SCALE 32767.0f
#define EW_INV (1.0f / 32767.0f)

// ---------------- prep: zero bcnt + pack both W's (one launch) ---------------
// Wpk[(((kt*4+la)*8)+nt)*16+ln][j] = bf16(W[k(j)][col]), k(j) = kt*32+la*4+
// (j&3)+16*(j>>2).

__global__ void k_prep(const float* __restrict__ W1, const float* __restrict__ Wmu,
                       const float* __restrict__ Wlv, unsigned short* __restrict__ P1,
                       unsigned short* __restrict__ P2, int* __restrict__ bcnt) {
    const int b = blockIdx.x, tid = threadIdx.x;
    if (b < 8) {
        int e = b * 256 + tid;  // 2048 entries
        int ln = e & 15, nt = (e >> 4) & 7, la = (e >> 7) & 3, kt = e >> 9;
        v8s v;
#pragma unroll
        for (int j = 0; j < 8; ++j) {
            int k = kt * 32 + la * 4 + (j & 3) + 16 * (j >> 2);
            v[j] = (short)f2bf(W1[k * 128 + nt * 16 + ln]);
        }
        *(v8s*)&P1[e * 8] = v;
    } else if (b < 16) {
        int e = (b - 8) * 256 + tid;
        int ln = e & 15, nt = (e >> 4) & 7, la = (e >> 7) & 3, kt = e >> 9;
        v8s v;
#pragma unroll
        for (int j = 0; j < 8; ++j) {
            int k = kt * 32 + la * 4 + (j & 3) + 16 * (j >> 2);
            float f = (nt < 4) ? Wmu[k * 64 + nt * 16 + ln]
                               : Wlv[k * 64 + (nt - 4) * 16 + ln];
            v[j] = (short)f2bf(f);
        }
        *(v8s*)&P2[e * 8] = v;
    } else {
        int i = (b - 16) * 256 + tid;
        if (i < NB * BSTRIDE) bcnt[i] = 0;
    }
}

// ---------------- build: block-local counting sort -> binned CSR -------------
// R1 lesson: global bucket-appends do NOT write-combine (non-coherent XCD L2s).

__launch_bounds__(256)
__global__ void k_bin(const int* __restrict__ row, const int* __restrict__ col,
                      const float* __restrict__ ew, int* __restrict__ bcnt,
                      uint2* __restrict__ bins) {
    __shared__ uint2 sorted[CHUNK];   // 16 KB bucket-sorted staging
    __shared__ int hist[NB];
    __shared__ int lstart[NB];
    __shared__ int offs[NB];
    __shared__ int gbase[NB];
    const int tid = threadIdx.x;
    const int ebase = blockIdx.x * CHUNK;
    const int nloc = (NE - ebase < CHUNK) ? (NE - ebase) : CHUNK;

    hist[tid] = 0;
    __syncthreads();

    // pass A: histogram destination buckets; cache cols in registers
    uint_t cols[CPT];
#pragma unroll
    for (int k = 0; k < CPT; ++k) {
        int i = ebase + k * 256 + tid;
        cols[k] = (i < NE) ? (uint_t)col[i] : 0xffffffffu;
        if (i < NE) atomicAdd(&hist[cols[k] / NPB], 1);
    }
    __syncthreads();

    // inclusive Hillis-Steele scan over 256 counters
    int v = hist[tid];
#pragma unroll
    for (int s = 1; s < NB; s <<= 1) {
        int t = (tid >= s) ? hist[tid - s] : 0;
        __syncthreads();
        hist[tid] += t;
        __syncthreads();
    }
    int excl = hist[tid] - v;
    lstart[tid] = excl;
    offs[tid] = excl;
    gbase[tid] = atomicAdd(&bcnt[tid * BSTRIDE], v);
    __syncthreads();

    // pass B: place records bucket-sorted into LDS
#pragma unroll
    for (int k = 0; k < CPT; ++k) {
        int i = ebase + k * 256 + tid;
        if (i < NE) {
            uint_t c = cols[k];
            uint_t r = (uint_t)row[i];
            uint_t q = (uint_t)__float2int_rn(ew[i] * EW_SCALE);
            int pos = atomicAdd(&offs[c / NPB], 1);
            sorted[pos] = make_uint2((r << 15) | q, c);
        }
    }
    __syncthreads();

    // flush: consecutive i within a bucket -> consecutive global addresses
    for (int i = tid; i < nloc; i += 256) {
        uint2 rec = sorted[i];
        uint_t b = rec.y / NPB;
        int dst = gbase[b] + (i - lstart[b]);
        if (dst < BCAP) bins[(size_t)b * BCAP + dst] = rec;
    }
}

// Phase 2: per-bucket slot placement; zero-pad each node's slot segment to
// roundup16(c) ((row=self, q=0) records) and publish cnt = roundup16(c) so
// the gather needs NO clamps (padded entries contribute exactly +0.0).

__launch_bounds__(512)
__global__ void k_scatter(const int* __restrict__ bcnt, const uint2* __restrict__ bins,
                          int* __restrict__ cnt, uint_t* __restrict__ slots,
                          float* __restrict__ dinv) {
    __shared__ int combo[NPB];
    const int b = blockIdx.x;
    const int tid = threadIdx.x;
    if (tid < NPB) combo[tid] = 0;
    __syncthreads();
    int n = bcnt[b * BSTRIDE];
    n = (n < BCAP) ? n : BCAP;
    const int base = b * NPB;
    const uint2* seg = bins + (size_t)b * BCAP;
    for (int i = tid; i < n; i += 512) {
        uint2 rec = seg[i];
        int lc = (int)rec.y - base;
        uint_t w = rec.x & 0x7fffu;
        uint_t old = (uint_t)atomicAdd(&combo[lc], (int)((1u << 22) | w));
        uint_t pos = old >> 22;
        if (pos < CAP) slots[rec.y * CAP + pos] = rec.x;
    }
    __syncthreads();
    if (tid < NPB) {
        int node = base + tid;
        if (node < NN) {
            uint_t v = (uint_t)combo[tid];
            int c = (int)(v >> 22);
            c = (c < CAP) ? c : CAP;
            int cp = (c + 15) & ~15;     // padded count (avg +8 pads)
            cnt[node] = cp;
            dinv[node] = rsqrtf(1.0f + (float)(v & 0x3fffffu) * EW_INV);
            uint_t padrec = (uint_t)node << 15;  // row=self, q=0 -> adds +0.0
            for (int j = c; j < cp; ++j) slots[node * CAP + j] = padrec;
        }
    }
}

// ---------------- gather (layer 1): one wave per node, clamp-free ------------
// R11 analysis: 63us == fill-path floor for this structure (194MB of L2 fills
// = 8-XCD replication of the 25.6MB y matrix) at 3.9TB/s combined.

template <bool RELU, bool OUT_BF16>
__launch_bounds__(256)
__global__ void k_gather(const uint_t* __restrict__ src, const int* __restrict__ cnt,
                         const uint_t* __restrict__ slots, const float* __restrict__ dinv,
                         const float* __restrict__ bias, void* __restrict__ dst) {
    int wid = (blockIdx.x * blockDim.x + threadIdx.x) >> 6;  // node id
    int lane = threadIdx.x & 63;
    if (wid >= NN) return;
    float di = dinv[wid];
    uint_t u = src[wid * 64 + lane];
    float accx = bf_lo(u);
    float accy = bf_hi(u);
    int end = __builtin_amdgcn_readfirstlane(cnt[wid]);  // multiple of 16, <= CAP
    const uint_t* seg = slots + wid * CAP;
    for (int jj = 0; jj < end; jj += 16) {
        uint_t rp[16];
#pragma unroll
        for (int q = 0; q < 16; ++q) rp[q] = seg[jj + q];  // padded: no clamp
        uint_t sv[16];
#pragma unroll
        for (int q = 0; q < 16; ++q) sv[q] = src[(rp[q] >> 15) * 64 + lane];
#pragma unroll
        for (int q = 0; q < 16; ++q) {
            float p = (float)(rp[q] & 0x7fffu) * EW_INV;   // padded: p == 0
            accx = fmaf(p, bf_lo(sv[q]), accx);
            accy = fmaf(p, bf_hi(sv[q]), accy);
        }
    }
    accx *= di;
    accy *= di;
    if (RELU) {
        float2 b = ((const float2*)bias)[lane];
        accx = fmaxf(accx + b.x, 0.0f) * di;  // prescale for next layer
        accy = fmaxf(accy + b.y, 0.0f) * di;
    }
    if (OUT_BF16) {
        ((uint_t*)dst)[wid * 64 + lane] =
            (uint_t)f2bf(accx) | ((uint_t)f2bf(accy) << 16);
    } else {
        ((float2*)dst)[wid * 64 + lane] = make_float2(accx, accy);
    }
}

// ------------- MFMA GEMM h0: 16x16x32 bf16, A split hi+lo, packed B ----------
// A (fp32) split hi+lo bf16 (2 MFMAs, residual ~2^-17); B pre-packed bf16.
// k-convention k = kt*32 + la*4 + (j&3) + 16*(j>>2) identical for A and B.
// C/D: col=lane&15, row=(lane>>4)*4+reg (m89-verified).

__launch_bounds__(256, 5)
__global__ void k_gemm_h0(const float* __restrict__ X,
                          const unsigned short* __restrict__ Wpk,
                          const float* __restrict__ dinv,
                          unsigned short* __restrict__ Y) {
    __shared__ float xs[GNM * 128];     // 32 KB, f4-index XOR-swizzled
    const int tid = threadIdx.x;
    const int node0 = blockIdx.x * GNM;

    {
        const float4* X4 = (const float4*)X;
        float4* xs4 = (float4*)xs;
        for (int i = tid; i < GNM * 32; i += 256) {
            int row = i >> 5, kg = i & 31;  // coalesced: 512B contiguous per row
            int ne = node0 + row;
            if (ne >= NN) ne = NN - 1;      // clamp: dup read, store predicated
            xs4[row * 32 + (kg ^ (row & 7))] = X4[ne * 32 + kg];
        }
    }
    __syncthreads();

    const int wave = tid >> 6, lane = tid & 63;
    const int la = lane >> 4, ln = lane & 15;
    const int lx = ln & 7;                // (wave*16+ln)&7 == ln&7
    const float* xrow = &xs[(wave * 16 + ln) * 128];
    const v8s* Wf = (const v8s*)Wpk;

    v4f acc[8];
#pragma unroll
    for (int nt = 0; nt < 8; ++nt) acc[nt] = (v4f){0.f, 0.f, 0.f, 0.f};

    for (int kt = 0; kt < 4; ++kt) {
        float4 xa0 = *(const float4*)&xrow[((kt * 8 + la) ^ lx) << 2];
        float4 xa1 = *(const float4*)&xrow[((kt * 8 + la + 4) ^ lx) << 2];
        float xv[8] = {xa0.x, xa0.y, xa0.z, xa0.w, xa1.x, xa1.y, xa1.z, xa1.w};
        v8s ah, al;
#pragma unroll
        for (int j = 0; j < 8; ++j) {
            unsigned short h = f2bf(xv[j]);
            ah[j] = (short)h;
            al[j] = (short)f2bf(xv[j] - bf2f(h));
        }
        const int wbase = (kt * 4 + la) * 8 * 16;
#pragma unroll
        for (int nt = 0; nt < 8; ++nt) {
            v8s bh = Wf[wbase + nt * 16 + ln];
            acc[nt] = __builtin_amdgcn_mfma_f32_16x16x32_bf16(ah, bh, acc[nt], 0, 0, 0);
            acc[nt] = __builtin_amdgcn_mfma_f32_16x16x32_bf16(al, bh, acc[nt], 0, 0, 0);
        }
    }

    // C/D: row = la*4 + r (node), col = ln. Y[node][128] bf16.
#pragma unroll
    for (int r = 0; r < 4; ++r) {
        int node = node0 + wave * 16 + la * 4 + r;
        if (node < NN) {
            float di = dinv[node];
#pragma unroll
            for (int nt = 0; nt < 8; ++nt)
                Y[node * 128 + nt * 16 + ln] = f2bf(acc[nt][r] * di);
        }
    }
}

// ------ fused gather2 + gemm_out: aggregate y1 -> swizzled LDS -> MFMA -------
// R14 lesson: at 32KB LDS the occupancy counter did NOT move (32%) and dur
// held at 88.6us — phase 1 is per-wave ILP-bound (2.7 TB/s vs the standalone
// gather's 3.86): the 16-node serial loop puts each node's seg->sv->fma chain
// end-to-end. R15: process nodes as 8 PAIRS with 8-deep unroll per node —
// two independent load chains per wave, each chain's FMA tail hides the
// other's load head. Per-node accumulation order unchanged -> bit-identical.

__launch_bounds__(256, 5)
__global__ void k_gg_out(const uint_t* __restrict__ src, const int* __restrict__ cnt,
                         const uint_t* __restrict__ slots, const float* __restrict__ dinv,
                         const unsigned short* __restrict__ Wpk,
                         const float* __restrict__ bmu, const float* __restrict__ blv,
                         float* __restrict__ out) {
    __shared__ float xs[GNM * 128];     // 32 KB, f4-index XOR-swizzled
    const int tid = threadIdx.x;
    const int node0 = blockIdx.x * GNM;
    const int wave = tid >> 6, lane = tid & 63;

    // phase 1: 8 node-pairs per wave, interleaved chunk loops.
    for (int m = 0; m < 8; ++m) {
        const int na = node0 + wave * 16 + 2 * m;
        const int nb = na + 1;
        const int ca = (na < NN) ? na : NN - 1;   // clamp: loads valid,
        const int cb = (nb < NN) ? nb : NN - 1;   // result zeroed below
        float dia = dinv[ca], dib = dinv[cb];
        uint_t ua = src[ca * 64 + lane];
        uint_t ub = src[cb * 64 + lane];
        float ax = bf_lo(ua), ay = bf_hi(ua);
        float bx = bf_lo(ub), by = bf_hi(ub);
        int ea = __builtin_amdgcn_readfirstlane(cnt[ca]);  // mult of 16
        int eb = __builtin_amdgcn_readfirstlane(cnt[cb]);
        const uint_t* sa = slots + ca * CAP;
        const uint_t* sb = slots + cb * CAP;
        int emax = (ea > eb) ? ea : eb;
        for (int jj = 0; jj < emax; jj += 8) {
            const bool da = jj < ea, db = jj < eb;  // wave-uniform
            uint_t rpa[8], rpb[8];
            if (da) {
#pragma unroll
                for (int q = 0; q < 8; ++q) rpa[q] = sa[jj + q];
            }
            if (db) {
#pragma unroll
                for (int q = 0; q < 8; ++q) rpb[q] = sb[jj + q];
            }
            uint_t sva[8], svb[8];
            if (da) {
#pragma unroll
                for (int q = 0; q < 8; ++q) sva[q] = src[(rpa[q] >> 15) * 64 + lane];
            }
            if (db) {
#pragma unroll
                for (int q = 0; q < 8; ++q) svb[q] = src[(rpb[q] >> 15) * 64 + lane];
            }
            if (da) {
#pragma unroll
                for (int q = 0; q < 8; ++q) {
                    float p = (float)(rpa[q] & 0x7fffu) * EW_INV;
                    ax = fmaf(p, bf_lo(sva[q]), ax);
                    ay = fmaf(p, bf_hi(sva[q]), ay);
                }
            }
            if (db) {
#pragma unroll
                for (int q = 0; q < 8; ++q) {
                    float p = (float)(rpb[q] & 0x7fffu) * EW_INV;
                    bx = fmaf(p, bf_lo(svb[q]), bx);
                    by = fmaf(p, bf_hi(svb[q]), by);
                }
            }
        }
        ax *= dia; ay *= dia;
        bx *= dib; by *= dib;
        if (na >= NN) { ax = 0.0f; ay = 0.0f; }
        if (nb >= NN) { bx = 0.0f; by = 0.0f; }
        // LDS store at swizzled f4 index: (r&7) == (2m|0/1)&7
        int ra = wave * 16 + 2 * m, rb = ra + 1;
        int f4a = (lane >> 1) ^ (ra & 7);
        int f4b = (lane >> 1) ^ (rb & 7);
        *(float2*)&xs[ra * 128 + (f4a << 2) + ((lane & 1) << 1)] = make_float2(ax, ay);
        *(float2*)&xs[rb * 128 + (f4b << 2) + ((lane & 1) << 1)] = make_float2(bx, by);
    }
    __syncthreads();

    // phase 2: MFMA epilogue (identical math to the split k_gemm_out)
    const int la = lane >> 4, ln = lane & 15;
    const int lx = ln & 7;
    const float* xrow = &xs[(wave * 16 + ln) * 128];
    const v8s* Wf = (const v8s*)Wpk;

    v4f acc[8];
#pragma unroll
    for (int nt = 0; nt < 8; ++nt) acc[nt] = (v4f){0.f, 0.f, 0.f, 0.f};

    for (int kt = 0; kt < 4; ++kt) {
        float4 xa0 = *(const float4*)&xrow[((kt * 8 + la) ^ lx) << 2];
        float4 xa1 = *(const float4*)&xrow[((kt * 8 + la + 4) ^ lx) << 2];
        float xv[8] = {xa0.x, xa0.y, xa0.z, xa0.w, xa1.x, xa1.y, xa1.z, xa1.w};
        v8s ah, al;
#pragma unroll
        for (int j = 0; j < 8; ++j) {
            unsigned short h = f2bf(xv[j]);
            ah[j] = (short)h;
            al[j] = (short)f2bf(xv[j] - bf2f(h));
        }
        const int wbase = (kt * 4 + la) * 8 * 16;
#pragma unroll
        for (int nt = 0; nt < 8; ++nt) {
            v8s bh = Wf[wbase + nt * 16 + ln];
            acc[nt] = __builtin_amdgcn_mfma_f32_16x16x32_bf16(ah, bh, acc[nt], 0, 0, 0);
            acc[nt] = __builtin_amdgcn_mfma_f32_16x16x32_bf16(al, bh, acc[nt], 0, 0, 0);
        }
    }

    float bb[8];
#pragma unroll
    for (int nt = 0; nt < 8; ++nt)
        bb[nt] = (nt < 4) ? bmu[nt * 16 + ln] : blv[(nt - 4) * 16 + ln];

#pragma unroll
    for (int r = 0; r < 4; ++r) {
        int node = node0 + wave * 16 + la * 4 + r;
        if (node < NN) {
#pragma unroll
            for (int nt = 0; nt < 8; ++nt) {
                float v = acc[nt][r] + bb[nt];
                if (nt < 4)
                    out[node * 64 + nt * 16 + ln] = v;
                else
                    out[OUT_HALF + node * 64 + (nt - 4) * 16 + ln] = v;
            }
        }
    }
}

// ---------------- launch ----------------

extern "C" void kernel_launch(void* const* d_in, const int* in_sizes, int n_in,
                              void* d_out, int out_size, void* d_ws, size_t ws_size,
                              hipStream_t stream) {
    const float* x   = (const float*)d_in[0];
    const int*   ei  = (const int*)d_in[1];   // [2, NE] int32 on device
    const float* ew  = (const float*)d_in[2];
    const float* W1  = (const float*)d_in[3];
    const float* b1  = (const float*)d_in[4];
    const float* Wmu = (const float*)d_in[5];
    const float* bmu = (const float*)d_in[6];
    const float* Wlv = (const float*)d_in[7];
    const float* blv = (const float*)d_in[8];
    const int* rowi = ei;        // sources
    const int* coli = ei + NE;   // destinations
    float* out = (float*)d_out;

    // workspace layout (4B elements). Liveness plan:
    //   prep:      Wpk1 -> hole at poolA+NN*64, Wpk2 -> hole+8K floats;
    //              bcnt zeroed. Hole [NN*64..NN*128) is NEVER aliased: bins
    //              overlay ends at 4.3M ints < NN*64 = 6.4M; y0=[0..NN*64);
    //              y1=[NN*128..NN*192). Both Wpk's live to the end.
    //   build:     bins+bcnt overlay poolA[0..4.3M)    (dead after scatter)
    //   gemm_h0:   y0 = poolA[0..NN*64) uints (bf16 [node][128])
    //   gather1:   y1 = poolA[NN*128..NN*192) uints  (y0 dead after)
    //   gg_out:    reads y1 + Wpk2, writes d_out directly
    int*    cnt   = (int*)d_ws;                  // NN ints, pad 100352
    float*  dinv  = (float*)(cnt + 100352);      // NN floats, pad 100352
    uint_t* slots = (uint_t*)(dinv + 100352);    // NN*CAP uints (25.6 MB)
    float*  poolA = (float*)(slots + NN * CAP);  // NN*128 floats (51.2 MB)
    uint_t* y0    = (uint_t*)poolA;              // [NN][64] uints (bf16x2)
    uint_t* y1    = (uint_t*)(poolA + NN * DD);  // [NN][64] uints
    uint2*  bins  = (uint2*)poolA;               // NB*BCAP uint2 (16.8 MB)
    int*    bcnt  = (int*)(poolA + NB * BCAP * 2);   // NB*BSTRIDE ints (64 KB)
    unsigned short* Wpk1 = (unsigned short*)(poolA + NN * 64);         // 32 KB
    unsigned short* Wpk2 = (unsigned short*)(poolA + NN * 64 + 8192);  // 32 KB

    const int B = 256;
    const int GGRID = (NN + GNM - 1) / GNM;  // 1563
    // one prep launch: pack W1 -> Wpk1, [Wmu|Wlv] -> Wpk2, zero bcnt
    k_prep<<<80, B, 0, stream>>>(W1, Wmu, Wlv, Wpk1, Wpk2, bcnt);
    k_bin<<<(NE + CHUNK - 1) / CHUNK, B, 0, stream>>>(rowi, coli, ew, bcnt, bins);
    k_scatter<<<NB, 512, 0, stream>>>(bcnt, bins, cnt, slots, dinv);
    // layer 1 (MFMA): y0 = dinv .* (x @ W1) -> bf16 [node][128]
    k_gemm_h0<<<GGRID, B, 0, stream>>>(x, Wpk1, dinv, (unsigned short*)y0);
    // y1 = dinv .* relu(dinv .* (y0[c] + sum ew*y0[r]) + b1) -> bf16
    k_gather<true, true><<<(NN * 64 + B - 1) / B, B, 0, stream>>>(
        y0, cnt, slots, dinv, b1, y1);
    // fused: aggregate y1 -> LDS -> MFMA -> [mu|logvar] (no g round-trip)
    k_gg_out<<<GGRID, B, 0, stream>>>(y1, cnt, slots, dinv, Wpk2, bmu, blv, out);
}

// Round 16
// 325.355 us; speedup vs baseline: 1.0295x; 1.0295x over previous
//
#include <hip/hip_runtime.h>

#define NN 100000
#define NE 1600000
#define DD 128            // IN_DIM == HID == 128
#define OUT_HALF 6400000  // NN * 64
#define CAP 64            // slots per node (max degree on this fixed graph ~42)

// ---- binned-build parameters ----
#define NB 256            // coarse destination buckets (== k_bin block size)
#define NPB 391           // nodes per bucket (256*391 = 100096 >= NN)
#define BCAP 8192         // record capacity per bucket (E[n]=6250, +24 sigma)
#define BSTRIDE 64        // ints between bucket counters (256B apart)
#define CHUNK 2048        // edges per k_bin block (782 blocks = 3/CU)
#define CPT 8             // CHUNK / 256

// ---- MFMA GEMM tile: 64 nodes/block, 4 waves, wave = 16 nodes x 128 cols ----
// LDS tile is exactly 64x128 fp32 = 32 KB with an XOR swizzle on the float4
// index (f4 ^ (row&7)) -> conflict-free; b128 reads 8 lanes/quad uniform.
#define GNM 64            // nodes per block

typedef unsigned int uint_t;
typedef float v4f __attribute__((ext_vector_type(4)));
typedef short v8s __attribute__((ext_vector_type(8)));

// round-to-nearest-even fp32 -> bf16 (as ushort)
__device__ __forceinline__ unsigned short f2bf(float f) {
    uint_t u = __float_as_uint(f);
    u = (u + 0x7fffu + ((u >> 16) & 1u)) >> 16;
    return (unsigned short)u;
}
__device__ __forceinline__ float bf2f(unsigned short h) {
    return __uint_as_float(((uint_t)h) << 16);
}
__device__ __forceinline__ float bf_lo(uint_t u) { return __uint_as_float(u << 16); }
__device__ __forceinline__ float bf_hi(uint_t u) { return __uint_as_float(u & 0xffff0000u); }

#define EW_SCALE 32767.0f
#define EW_INV (1.0f / 32767.0f)

// ---------------- prep: zero bcnt + pack both W's (one launch) ---------------
// Wpk[(((kt*4+la)*8)+nt)*16+ln][j] = bf16(W[k(j)][col]), k(j) = kt*32+la*4+
// (j&3)+16*(j>>2).

__global__ void k_prep(const float* __restrict__ W1, const float* __restrict__ Wmu,
                       const float* __restrict__ Wlv, unsigned short* __restrict__ P1,
                       unsigned short* __restrict__ P2, int* __restrict__ bcnt) {
    const int b = blockIdx.x, tid = threadIdx.x;
    if (b < 8) {
        int e = b * 256 + tid;  // 2048 entries
        int ln = e & 15, nt = (e >> 4) & 7, la = (e >> 7) & 3, kt = e >> 9;
        v8s v;
#pragma unroll
        for (int j = 0; j < 8; ++j) {
            int k = kt * 32 + la * 4 + (j & 3) + 16 * (j >> 2);
            v[j] = (short)f2bf(W1[k * 128 + nt * 16 + ln]);
        }
        *(v8s*)&P1[e * 8] = v;
    } else if (b < 16) {
        int e = (b - 8) * 256 + tid;
        int ln = e & 15, nt = (e >> 4) & 7, la = (e >> 7) & 3, kt = e >> 9;
        v8s v;
#pragma unroll
        for (int j = 0; j < 8; ++j) {
            int k = kt * 32 + la * 4 + (j & 3) + 16 * (j >> 2);
            float f = (nt < 4) ? Wmu[k * 64 + nt * 16 + ln]
                               : Wlv[k * 64 + (nt - 4) * 16 + ln];
            v[j] = (short)f2bf(f);
        }
        *(v8s*)&P2[e * 8] = v;
    } else {
        int i = (b - 16) * 256 + tid;
        if (i < NB * BSTRIDE) bcnt[i] = 0;
    }
}

// ---------------- build: block-local counting sort -> binned CSR -------------
// R1 lesson: global bucket-appends do NOT write-combine (non-coherent XCD L2s).

__launch_bounds__(256)
__global__ void k_bin(const int* __restrict__ row, const int* __restrict__ col,
                      const float* __restrict__ ew, int* __restrict__ bcnt,
                      uint2* __restrict__ bins) {
    __shared__ uint2 sorted[CHUNK];   // 16 KB bucket-sorted staging
    __shared__ int hist[NB];
    __shared__ int lstart[NB];
    __shared__ int offs[NB];
    __shared__ int gbase[NB];
    const int tid = threadIdx.x;
    const int ebase = blockIdx.x * CHUNK;
    const int nloc = (NE - ebase < CHUNK) ? (NE - ebase) : CHUNK;

    hist[tid] = 0;
    __syncthreads();

    // pass A: histogram destination buckets; cache cols in registers
    uint_t cols[CPT];
#pragma unroll
    for (int k = 0; k < CPT; ++k) {
        int i = ebase + k * 256 + tid;
        cols[k] = (i < NE) ? (uint_t)col[i] : 0xffffffffu;
        if (i < NE) atomicAdd(&hist[cols[k] / NPB], 1);
    }
    __syncthreads();

    // inclusive Hillis-Steele scan over 256 counters
    int v = hist[tid];
#pragma unroll
    for (int s = 1; s < NB; s <<= 1) {
        int t = (tid >= s) ? hist[tid - s] : 0;
        __syncthreads();
        hist[tid] += t;
        __syncthreads();
    }
    int excl = hist[tid] - v;
    lstart[tid] = excl;
    offs[tid] = excl;
    gbase[tid] = atomicAdd(&bcnt[tid * BSTRIDE], v);
    __syncthreads();

    // pass B: place records bucket-sorted into LDS
#pragma unroll
    for (int k = 0; k < CPT; ++k) {
        int i = ebase + k * 256 + tid;
        if (i < NE) {
            uint_t c = cols[k];
            uint_t r = (uint_t)row[i];
            uint_t q = (uint_t)__float2int_rn(ew[i] * EW_SCALE);
            int pos = atomicAdd(&offs[c / NPB], 1);
            sorted[pos] = make_uint2((r << 15) | q, c);
        }
    }
    __syncthreads();

    // flush: consecutive i within a bucket -> consecutive global addresses
    for (int i = tid; i < nloc; i += 256) {
        uint2 rec = sorted[i];
        uint_t b = rec.y / NPB;
        int dst = gbase[b] + (i - lstart[b]);
        if (dst < BCAP) bins[(size_t)b * BCAP + dst] = rec;
    }
}

// Phase 2: per-bucket slot placement. R16: zero-pad each node's slot segment
// ALL THE WAY to CAP ((row=self, q=0) records -> contribute exactly +0.0) so
// the fused gather can run branch-free pair loops to max(ea,eb). cnt stays
// roundup16(c) so gather1's trip count is minimal.

__launch_bounds__(512)
__global__ void k_scatter(const int* __restrict__ bcnt, const uint2* __restrict__ bins,
                          int* __restrict__ cnt, uint_t* __restrict__ slots,
                          float* __restrict__ dinv) {
    __shared__ int combo[NPB];
    const int b = blockIdx.x;
    const int tid = threadIdx.x;
    if (tid < NPB) combo[tid] = 0;
    __syncthreads();
    int n = bcnt[b * BSTRIDE];
    n = (n < BCAP) ? n : BCAP;
    const int base = b * NPB;
    const uint2* seg = bins + (size_t)b * BCAP;
    for (int i = tid; i < n; i += 512) {
        uint2 rec = seg[i];
        int lc = (int)rec.y - base;
        uint_t w = rec.x & 0x7fffu;
        uint_t old = (uint_t)atomicAdd(&combo[lc], (int)((1u << 22) | w));
        uint_t pos = old >> 22;
        if (pos < CAP) slots[rec.y * CAP + pos] = rec.x;
    }
    __syncthreads();
    if (tid < NPB) {
        int node = base + tid;
        if (node < NN) {
            uint_t v = (uint_t)combo[tid];
            int c = (int)(v >> 22);
            c = (c < CAP) ? c : CAP;
            cnt[node] = (c + 15) & ~15;  // mult-of-16 count for gather1
            dinv[node] = rsqrtf(1.0f + (float)(v & 0x3fffffu) * EW_INV);
            uint_t padrec = (uint_t)node << 15;  // row=self, q=0 -> adds +0.0
            for (int j = c; j < CAP; ++j) slots[node * CAP + j] = padrec;
        }
    }
}

// ---------------- gather (layer 1): one wave per node, clamp-free ------------
// R11 analysis: 63us == fill-path floor for this structure (194MB of L2 fills
// = 8-XCD replication of the 25.6MB y matrix) at 3.9TB/s combined.

template <bool RELU, bool OUT_BF16>
__launch_bounds__(256)
__global__ void k_gather(const uint_t* __restrict__ src, const int* __restrict__ cnt,
                         const uint_t* __restrict__ slots, const float* __restrict__ dinv,
                         const float* __restrict__ bias, void* __restrict__ dst) {
    int wid = (blockIdx.x * blockDim.x + threadIdx.x) >> 6;  // node id
    int lane = threadIdx.x & 63;
    if (wid >= NN) return;
    float di = dinv[wid];
    uint_t u = src[wid * 64 + lane];
    float accx = bf_lo(u);
    float accy = bf_hi(u);
    int end = __builtin_amdgcn_readfirstlane(cnt[wid]);  // multiple of 16, <= CAP
    const uint_t* seg = slots + wid * CAP;
    for (int jj = 0; jj < end; jj += 16) {
        uint_t rp[16];
#pragma unroll
        for (int q = 0; q < 16; ++q) rp[q] = seg[jj + q];  // padded: no clamp
        uint_t sv[16];
#pragma unroll
        for (int q = 0; q < 16; ++q) sv[q] = src[(rp[q] >> 15) * 64 + lane];
#pragma unroll
        for (int q = 0; q < 16; ++q) {
            float p = (float)(rp[q] & 0x7fffu) * EW_INV;   // padded: p == 0
            accx = fmaf(p, bf_lo(sv[q]), accx);
            accy = fmaf(p, bf_hi(sv[q]), accy);
        }
    }
    accx *= di;
    accy *= di;
    if (RELU) {
        float2 b = ((const float2*)bias)[lane];
        accx = fmaxf(accx + b.x, 0.0f) * di;  // prescale for next layer
        accy = fmaxf(accy + b.y, 0.0f) * di;
    }
    if (OUT_BF16) {
        ((uint_t*)dst)[wid * 64 + lane] =
            (uint_t)f2bf(accx) | ((uint_t)f2bf(accy) << 16);
    } else {
        ((float2*)dst)[wid * 64 + lane] = make_float2(accx, accy);
    }
}

// ------------- MFMA GEMM h0: 16x16x32 bf16, A split hi+lo, packed B ----------
// A (fp32) split hi+lo bf16 (2 MFMAs, residual ~2^-17); B pre-packed bf16.
// k-convention k = kt*32 + la*4 + (j&3) + 16*(j>>2) identical for A and B.
// C/D: col=lane&15, row=(lane>>4)*4+reg (m89-verified).

__launch_bounds__(256, 5)
__global__ void k_gemm_h0(const float* __restrict__ X,
                          const unsigned short* __restrict__ Wpk,
                          const float* __restrict__ dinv,
                          unsigned short* __restrict__ Y) {
    __shared__ float xs[GNM * 128];     // 32 KB, f4-index XOR-swizzled
    const int tid = threadIdx.x;
    const int node0 = blockIdx.x * GNM;

    {
        const float4* X4 = (const float4*)X;
        float4* xs4 = (float4*)xs;
        for (int i = tid; i < GNM * 32; i += 256) {
            int row = i >> 5, kg = i & 31;  // coalesced: 512B contiguous per row
            int ne = node0 + row;
            if (ne >= NN) ne = NN - 1;      // clamp: dup read, store predicated
            xs4[row * 32 + (kg ^ (row & 7))] = X4[ne * 32 + kg];
        }
    }
    __syncthreads();

    const int wave = tid >> 6, lane = tid & 63;
    const int la = lane >> 4, ln = lane & 15;
    const int lx = ln & 7;                // (wave*16+ln)&7 == ln&7
    const float* xrow = &xs[(wave * 16 + ln) * 128];
    const v8s* Wf = (const v8s*)Wpk;

    v4f acc[8];
#pragma unroll
    for (int nt = 0; nt < 8; ++nt) acc[nt] = (v4f){0.f, 0.f, 0.f, 0.f};

    for (int kt = 0; kt < 4; ++kt) {
        float4 xa0 = *(const float4*)&xrow[((kt * 8 + la) ^ lx) << 2];
        float4 xa1 = *(const float4*)&xrow[((kt * 8 + la + 4) ^ lx) << 2];
        float xv[8] = {xa0.x, xa0.y, xa0.z, xa0.w, xa1.x, xa1.y, xa1.z, xa1.w};
        v8s ah, al;
#pragma unroll
        for (int j = 0; j < 8; ++j) {
            unsigned short h = f2bf(xv[j]);
            ah[j] = (short)h;
            al[j] = (short)f2bf(xv[j] - bf2f(h));
        }
        const int wbase = (kt * 4 + la) * 8 * 16;
#pragma unroll
        for (int nt = 0; nt < 8; ++nt) {
            v8s bh = Wf[wbase + nt * 16 + ln];
            acc[nt] = __builtin_amdgcn_mfma_f32_16x16x32_bf16(ah, bh, acc[nt], 0, 0, 0);
            acc[nt] = __builtin_amdgcn_mfma_f32_16x16x32_bf16(al, bh, acc[nt], 0, 0, 0);
        }
    }

    // C/D: row = la*4 + r (node), col = ln. Y[node][128] bf16.
#pragma unroll
    for (int r = 0; r < 4; ++r) {
        int node = node0 + wave * 16 + la * 4 + r;
        if (node < NN) {
            float di = dinv[node];
#pragma unroll
            for (int nt = 0; nt < 8; ++nt)
                Y[node * 128 + nt * 16 + ln] = f2bf(acc[nt][r] * di);
        }
    }
}

// ------ fused gather2 + gemm_out: aggregate y1 -> swizzled LDS -> MFMA -------
// R15 lesson: the if(da)/if(db) pair interleave compiled to SEQUENTIAL blocks
// (VGPR stayed 44, dur 112us) — hipcc won't interleave across wave-uniform
// branches. R16: full-CAP padded slots make the pair loop BRANCH-FREE to
// emax = max(ea,eb); the shorter node's extra iterations are fma(0,y,acc)
// = acc exactly -> bit-identical. Two independent 8-deep chains per wave.

__launch_bounds__(256, 5)
__global__ void k_gg_out(const uint_t* __restrict__ src, const int* __restrict__ cnt,
                         const uint_t* __restrict__ slots, const float* __restrict__ dinv,
                         const unsigned short* __restrict__ Wpk,
                         const float* __restrict__ bmu, const float* __restrict__ blv,
                         float* __restrict__ out) {
    __shared__ float xs[GNM * 128];     // 32 KB, f4-index XOR-swizzled
    const int tid = threadIdx.x;
    const int node0 = blockIdx.x * GNM;
    const int wave = tid >> 6, lane = tid & 63;

    // phase 1: 8 node-pairs per wave, branch-free interleaved chunk loops.
    for (int m = 0; m < 8; ++m) {
        const int na = node0 + wave * 16 + 2 * m;
        const int nb = na + 1;
        const int ca = (na < NN) ? na : NN - 1;   // clamp: loads valid,
        const int cb = (nb < NN) ? nb : NN - 1;   // result zeroed below
        float dia = dinv[ca], dib = dinv[cb];
        uint_t ua = src[ca * 64 + lane];
        uint_t ub = src[cb * 64 + lane];
        float ax = bf_lo(ua), ay = bf_hi(ua);
        float bx = bf_lo(ub), by = bf_hi(ub);
        int ea = __builtin_amdgcn_readfirstlane(cnt[ca]);
        int eb = __builtin_amdgcn_readfirstlane(cnt[cb]);
        const uint_t* sa = slots + ca * CAP;
        const uint_t* sb = slots + cb * CAP;
        int emax = (ea > eb) ? ea : eb;           // <= CAP; slots CAP-padded
        for (int jj = 0; jj < emax; jj += 8) {
            uint_t rpa[8], rpb[8];
#pragma unroll
            for (int q = 0; q < 8; ++q) rpa[q] = sa[jj + q];
#pragma unroll
            for (int q = 0; q < 8; ++q) rpb[q] = sb[jj + q];
            uint_t sva[8], svb[8];
#pragma unroll
            for (int q = 0; q < 8; ++q) sva[q] = src[(rpa[q] >> 15) * 64 + lane];
#pragma unroll
            for (int q = 0; q < 8; ++q) svb[q] = src[(rpb[q] >> 15) * 64 + lane];
#pragma unroll
            for (int q = 0; q < 8; ++q) {
                float pa = (float)(rpa[q] & 0x7fffu) * EW_INV;  // padded: 0
                ax = fmaf(pa, bf_lo(sva[q]), ax);
                ay = fmaf(pa, bf_hi(sva[q]), ay);
            }
#pragma unroll
            for (int q = 0; q < 8; ++q) {
                float pb = (float)(rpb[q] & 0x7fffu) * EW_INV;  // padded: 0
                bx = fmaf(pb, bf_lo(svb[q]), bx);
                by = fmaf(pb, bf_hi(svb[q]), by);
            }
        }
        ax *= dia; ay *= dia;
        bx *= dib; by *= dib;
        if (na >= NN) { ax = 0.0f; ay = 0.0f; }
        if (nb >= NN) { bx = 0.0f; by = 0.0f; }
        // LDS store at swizzled f4 index
        int ra = wave * 16 + 2 * m, rb = ra + 1;
        int f4a = (lane >> 1) ^ (ra & 7);
        int f4b = (lane >> 1) ^ (rb & 7);
        *(float2*)&xs[ra * 128 + (f4a << 2) + ((lane & 1) << 1)] = make_float2(ax, ay);
        *(float2*)&xs[rb * 128 + (f4b << 2) + ((lane & 1) << 1)] = make_float2(bx, by);
    }
    __syncthreads();

    // phase 2: MFMA epilogue (identical math to the split k_gemm_out)
    const int la = lane >> 4, ln = lane & 15;
    const int lx = ln & 7;
    const float* xrow = &xs[(wave * 16 + ln) * 128];
    const v8s* Wf = (const v8s*)Wpk;

    v4f acc[8];
#pragma unroll
    for (int nt = 0; nt < 8; ++nt) acc[nt] = (v4f){0.f, 0.f, 0.f, 0.f};

    for (int kt = 0; kt < 4; ++kt) {
        float4 xa0 = *(const float4*)&xrow[((kt * 8 + la) ^ lx) << 2];
        float4 xa1 = *(const float4*)&xrow[((kt * 8 + la + 4) ^ lx) << 2];
        float xv[8] = {xa0.x, xa0.y, xa0.z, xa0.w, xa1.x, xa1.y, xa1.z, xa1.w};
        v8s ah, al;
#pragma unroll
        for (int j = 0; j < 8; ++j) {
            unsigned short h = f2bf(xv[j]);
            ah[j] = (short)h;
            al[j] = (short)f2bf(xv[j] - bf2f(h));
        }
        const int wbase = (kt * 4 + la) * 8 * 16;
#pragma unroll
        for (int nt = 0; nt < 8; ++nt) {
            v8s bh = Wf[wbase + nt * 16 + ln];
            acc[nt] = __builtin_amdgcn_mfma_f32_16x16x32_bf16(ah, bh, acc[nt], 0, 0, 0);
            acc[nt] = __builtin_amdgcn_mfma_f32_16x16x32_bf16(al, bh, acc[nt], 0, 0, 0);
        }
    }

    float bb[8];
#pragma unroll
    for (int nt = 0; nt < 8; ++nt)
        bb[nt] = (nt < 4) ? bmu[nt * 16 + ln] : blv[(nt - 4) * 16 + ln];

#pragma unroll
    for (int r = 0; r < 4; ++r) {
        int node = node0 + wave * 16 + la * 4 + r;
        if (node < NN) {
#pragma unroll
            for (int nt = 0; nt < 8; ++nt) {
                float v = acc[nt][r] + bb[nt];
                if (nt < 4)
                    out[node * 64 + nt * 16 + ln] = v;
                else
                    out[OUT_HALF + node * 64 + (nt - 4) * 16 + ln] = v;
            }
        }
    }
}

// ---------------- launch ----------------

extern "C" void kernel_launch(void* const* d_in, const int* in_sizes, int n_in,
                              void* d_out, int out_size, void* d_ws, size_t ws_size,
                              hipStream_t stream) {
    const float* x   = (const float*)d_in[0];
    const int*   ei  = (const int*)d_in[1];   // [2, NE] int32 on device
    const float* ew  = (const float*)d_in[2];
    const float* W1  = (const float*)d_in[3];
    const float* b1  = (const float*)d_in[4];
    const float* Wmu = (const float*)d_in[5];
    const float* bmu = (const float*)d_in[6];
    const float* Wlv = (const float*)d_in[7];
    const float* blv = (const float*)d_in[8];
    const int* rowi = ei;        // sources
    const int* coli = ei + NE;   // destinations
    float* out = (float*)d_out;

    // workspace layout (4B elements). Liveness plan:
    //   prep:      Wpk1 -> hole at poolA+NN*64, Wpk2 -> hole+8K floats;
    //              bcnt zeroed. Hole [NN*64..NN*128) is NEVER aliased: bins
    //              overlay ends at 4.3M ints < NN*64 = 6.4M; y0=[0..NN*64);
    //              y1=[NN*128..NN*192). Both Wpk's live to the end.
    //   build:     bins+bcnt overlay poolA[0..4.3M)    (dead after scatter)
    //   gemm_h0:   y0 = poolA[0..NN*64) uints (bf16 [node][128])
    //   gather1:   y1 = poolA[NN*128..NN*192) uints  (y0 dead after)
    //   gg_out:    reads y1 + Wpk2, writes d_out directly
    int*    cnt   = (int*)d_ws;                  // NN ints, pad 100352
    float*  dinv  = (float*)(cnt + 100352);      // NN floats, pad 100352
    uint_t* slots = (uint_t*)(dinv + 100352);    // NN*CAP uints (25.6 MB)
    float*  poolA = (float*)(slots + NN * CAP);  // NN*128 floats (51.2 MB)
    uint_t* y0    = (uint_t*)poolA;              // [NN][64] uints (bf16x2)
    uint_t* y1    = (uint_t*)(poolA + NN * DD);  // [NN][64] uints
    uint2*  bins  = (uint2*)poolA;               // NB*BCAP uint2 (16.8 MB)
    int*    bcnt  = (int*)(poolA + NB * BCAP * 2);   // NB*BSTRIDE ints (64 KB)
    unsigned short* Wpk1 = (unsigned short*)(poolA + NN * 64);         // 32 KB
    unsigned short* Wpk2 = (unsigned short*)(poolA + NN * 64 + 8192);  // 32 KB

    const int B = 256;
    const int GGRID = (NN + GNM - 1) / GNM;  // 1563
    // one prep launch: pack W1 -> Wpk1, [Wmu|Wlv] -> Wpk2, zero bcnt
    k_prep<<<80, B, 0, stream>>>(W1, Wmu, Wlv, Wpk1, Wpk2, bcnt);
    k_bin<<<(NE + CHUNK - 1) / CHUNK, B, 0, stream>>>(rowi, coli, ew, bcnt, bins);
    k_scatter<<<NB, 512, 0, stream>>>(bcnt, bins, cnt, slots, dinv);
    // layer 1 (MFMA): y0 = dinv .* (x @ W1) -> bf16 [node][128]
    k_gemm_h0<<<GGRID, B, 0, stream>>>(x, Wpk1, dinv, (unsigned short*)y0);
    // y1 = dinv .* relu(dinv .* (y0[c] + sum ew*y0[r]) + b1) -> bf16
    k_gather<true, true><<<(NN * 64 + B - 1) / B, B, 0, stream>>>(
        y0, cnt, slots, dinv, b1, y1);
    // fused: aggregate y1 -> LDS -> MFMA -> [mu|logvar] (no g round-trip)
    k_gg_out<<<GGRID, B, 0, stream>>>(y1, cnt, slots, dinv, Wpk2, bmu, blv, out);
}

// Round 17
// 307.379 us; speedup vs baseline: 1.0897x; 1.0585x over previous
//
#include <hip/hip_runtime.h>

#define NN 100000
#define NE 1600000
#define DD 128            // IN_DIM == HID == 128
#define OUT_HALF 6400000  // NN * 64
#define CAP 64            // slots per node (max degree on this fixed graph ~42)

// ---- binned-build parameters ----
#define NB 256            // coarse destination buckets (== k_bin block size)
#define NPB 391           // nodes per bucket (256*391 = 100096 >= NN)
#define BCAP 8192         // record capacity per bucket (E[n]=6250, +24 sigma)
#define BSTRIDE 64        // ints between bucket counters (256B apart)
#define CHUNK 2048        // edges per k_bin block (782 blocks = 3/CU)
#define CPT 8             // CHUNK / 256

// ---- MFMA GEMM tile: 64 nodes/block; LDS 64x128 fp32 = 32 KB, XOR-swizzled
// on the float4 index (f4 ^ (row&7)) -> conflict-free b128 reads.
#define GNM 64            // nodes per block

typedef unsigned int uint_t;
typedef float v4f __attribute__((ext_vector_type(4)));
typedef short v8s __attribute__((ext_vector_type(8)));

// round-to-nearest-even fp32 -> bf16 (as ushort)
__device__ __forceinline__ unsigned short f2bf(float f) {
    uint_t u = __float_as_uint(f);
    u = (u + 0x7fffu + ((u >> 16) & 1u)) >> 16;
    return (unsigned short)u;
}
__device__ __forceinline__ float bf2f(unsigned short h) {
    return __uint_as_float(((uint_t)h) << 16);
}
__device__ __forceinline__ float bf_lo(uint_t u) { return __uint_as_float(u << 16); }
__device__ __forceinline__ float bf_hi(uint_t u) { return __uint_as_float(u & 0xffff0000u); }

#define EW_SCALE 32767.0f
#define EW_INV (1.0f / 32767.0f)

// ---------------- prep: zero bcnt + pack both W's (one launch) ---------------
// Wpk[(((kt*4+la)*8)+nt)*16+ln][j] = bf16(W[k(j)][col]), k(j) = kt*32+la*4+
// (j&3)+16*(j>>2).

__global__ void k_prep(const float* __restrict__ W1, const float* __restrict__ Wmu,
                       const float* __restrict__ Wlv, unsigned short* __restrict__ P1,
                       unsigned short* __restrict__ P2, int* __restrict__ bcnt) {
    const int b = blockIdx.x, tid = threadIdx.x;
    if (b < 8) {
        int e = b * 256 + tid;  // 2048 entries
        int ln = e & 15, nt = (e >> 4) & 7, la = (e >> 7) & 3, kt = e >> 9;
        v8s v;
#pragma unroll
        for (int j = 0; j < 8; ++j) {
            int k = kt * 32 + la * 4 + (j & 3) + 16 * (j >> 2);
            v[j] = (short)f2bf(W1[k * 128 + nt * 16 + ln]);
        }
        *(v8s*)&P1[e * 8] = v;
    } else if (b < 16) {
        int e = (b - 8) * 256 + tid;
        int ln = e & 15, nt = (e >> 4) & 7, la = (e >> 7) & 3, kt = e >> 9;
        v8s v;
#pragma unroll
        for (int j = 0; j < 8; ++j) {
            int k = kt * 32 + la * 4 + (j & 3) + 16 * (j >> 2);
            float f = (nt < 4) ? Wmu[k * 64 + nt * 16 + ln]
                               : Wlv[k * 64 + (nt - 4) * 16 + ln];
            v[j] = (short)f2bf(f);
        }
        *(v8s*)&P2[e * 8] = v;
    } else {
        int i = (b - 16) * 256 + tid;
        if (i < NB * BSTRIDE) bcnt[i] = 0;
    }
}

// ---------------- build: block-local counting sort -> binned CSR -------------
// R1 lesson: global bucket-appends do NOT write-combine (non-coherent XCD L2s).

__launch_bounds__(256)
__global__ void k_bin(const int* __restrict__ row, const int* __restrict__ col,
                      const float* __restrict__ ew, int* __restrict__ bcnt,
                      uint2* __restrict__ bins) {
    __shared__ uint2 sorted[CHUNK];   // 16 KB bucket-sorted staging
    __shared__ int hist[NB];
    __shared__ int lstart[NB];
    __shared__ int offs[NB];
    __shared__ int gbase[NB];
    const int tid = threadIdx.x;
    const int ebase = blockIdx.x * CHUNK;
    const int nloc = (NE - ebase < CHUNK) ? (NE - ebase) : CHUNK;

    hist[tid] = 0;
    __syncthreads();

    // pass A: histogram destination buckets; cache cols in registers
    uint_t cols[CPT];
#pragma unroll
    for (int k = 0; k < CPT; ++k) {
        int i = ebase + k * 256 + tid;
        cols[k] = (i < NE) ? (uint_t)col[i] : 0xffffffffu;
        if (i < NE) atomicAdd(&hist[cols[k] / NPB], 1);
    }
    __syncthreads();

    // inclusive Hillis-Steele scan over 256 counters
    int v = hist[tid];
#pragma unroll
    for (int s = 1; s < NB; s <<= 1) {
        int t = (tid >= s) ? hist[tid - s] : 0;
        __syncthreads();
        hist[tid] += t;
        __syncthreads();
    }
    int excl = hist[tid] - v;
    lstart[tid] = excl;
    offs[tid] = excl;
    gbase[tid] = atomicAdd(&bcnt[tid * BSTRIDE], v);
    __syncthreads();

    // pass B: place records bucket-sorted into LDS
#pragma unroll
    for (int k = 0; k < CPT; ++k) {
        int i = ebase + k * 256 + tid;
        if (i < NE) {
            uint_t c = cols[k];
            uint_t r = (uint_t)row[i];
            uint_t q = (uint_t)__float2int_rn(ew[i] * EW_SCALE);
            int pos = atomicAdd(&offs[c / NPB], 1);
            sorted[pos] = make_uint2((r << 15) | q, c);
        }
    }
    __syncthreads();

    // flush: consecutive i within a bucket -> consecutive global addresses
    for (int i = tid; i < nloc; i += 256) {
        uint2 rec = sorted[i];
        uint_t b = rec.y / NPB;
        int dst = gbase[b] + (i - lstart[b]);
        if (dst < BCAP) bins[(size_t)b * BCAP + dst] = rec;
    }
}

// Phase 2: per-bucket slot placement; zero-pad each node's slot segment to
// roundup16(c) ((row=self, q=0) records) and publish cnt = roundup16(c) so
// both gathers run clamp-free (padded entries contribute exactly +0.0).

__launch_bounds__(512)
__global__ void k_scatter(const int* __restrict__ bcnt, const uint2* __restrict__ bins,
                          int* __restrict__ cnt, uint_t* __restrict__ slots,
                          float* __restrict__ dinv) {
    __shared__ int combo[NPB];
    const int b = blockIdx.x;
    const int tid = threadIdx.x;
    if (tid < NPB) combo[tid] = 0;
    __syncthreads();
    int n = bcnt[b * BSTRIDE];
    n = (n < BCAP) ? n : BCAP;
    const int base = b * NPB;
    const uint2* seg = bins + (size_t)b * BCAP;
    for (int i = tid; i < n; i += 512) {
        uint2 rec = seg[i];
        int lc = (int)rec.y - base;
        uint_t w = rec.x & 0x7fffu;
        uint_t old = (uint_t)atomicAdd(&combo[lc], (int)((1u << 22) | w));
        uint_t pos = old >> 22;
        if (pos < CAP) slots[rec.y * CAP + pos] = rec.x;
    }
    __syncthreads();
    if (tid < NPB) {
        int node = base + tid;
        if (node < NN) {
            uint_t v = (uint_t)combo[tid];
            int c = (int)(v >> 22);
            c = (c < CAP) ? c : CAP;
            int cp = (c + 15) & ~15;     // padded count (avg +8 pads)
            cnt[node] = cp;
            dinv[node] = rsqrtf(1.0f + (float)(v & 0x3fffffu) * EW_INV);
            uint_t padrec = (uint_t)node << 15;  // row=self, q=0 -> adds +0.0
            for (int j = c; j < cp; ++j) slots[node * CAP + j] = padrec;
        }
    }
}

// ---------------- gather (layer 1): one wave per node, clamp-free ------------
// R11 analysis: 63us == fill-path floor (194MB of L2 fills = 8-XCD
// replication of the 25.6MB y matrix) at 3.9TB/s and ~21 waves/CU.

template <bool RELU, bool OUT_BF16>
__launch_bounds__(256)
__global__ void k_gather(const uint_t* __restrict__ src, const int* __restrict__ cnt,
                         const uint_t* __restrict__ slots, const float* __restrict__ dinv,
                         const float* __restrict__ bias, void* __restrict__ dst) {
    int wid = (blockIdx.x * blockDim.x + threadIdx.x) >> 6;  // node id
    int lane = threadIdx.x & 63;
    if (wid >= NN) return;
    float di = dinv[wid];
    uint_t u = src[wid * 64 + lane];
    float accx = bf_lo(u);
    float accy = bf_hi(u);
    int end = __builtin_amdgcn_readfirstlane(cnt[wid]);  // multiple of 16, <= CAP
    const uint_t* seg = slots + wid * CAP;
    for (int jj = 0; jj < end; jj += 16) {
        uint_t rp[16];
#pragma unroll
        for (int q = 0; q < 16; ++q) rp[q] = seg[jj + q];  // padded: no clamp
        uint_t sv[16];
#pragma unroll
        for (int q = 0; q < 16; ++q) sv[q] = src[(rp[q] >> 15) * 64 + lane];
#pragma unroll
        for (int q = 0; q < 16; ++q) {
            float p = (float)(rp[q] & 0x7fffu) * EW_INV;   // padded: p == 0
            accx = fmaf(p, bf_lo(sv[q]), accx);
            accy = fmaf(p, bf_hi(sv[q]), accy);
        }
    }
    accx *= di;
    accy *= di;
    if (RELU) {
        float2 b = ((const float2*)bias)[lane];
        accx = fmaxf(accx + b.x, 0.0f) * di;  // prescale for next layer
        accy = fmaxf(accy + b.y, 0.0f) * di;
    }
    if (OUT_BF16) {
        ((uint_t*)dst)[wid * 64 + lane] =
            (uint_t)f2bf(accx) | ((uint_t)f2bf(accy) << 16);
    } else {
        ((float2*)dst)[wid * 64 + lane] = make_float2(accx, accy);
    }
}

// ------------- MFMA GEMM h0: 16x16x32 bf16, A split hi+lo, packed B ----------
// A (fp32) split hi+lo bf16 (2 MFMAs, residual ~2^-17); B pre-packed bf16.
// k-convention k = kt*32 + la*4 + (j&3) + 16*(j>>2) identical for A and B.
// C/D: col=lane&15, row=(lane>>4)*4+reg (m89-verified).

__launch_bounds__(256, 5)
__global__ void k_gemm_h0(const float* __restrict__ X,
                          const unsigned short* __restrict__ Wpk,
                          const float* __restrict__ dinv,
                          unsigned short* __restrict__ Y) {
    __shared__ float xs[GNM * 128];     // 32 KB, f4-index XOR-swizzled
    const int tid = threadIdx.x;
    const int node0 = blockIdx.x * GNM;

    {
        const float4* X4 = (const float4*)X;
        float4* xs4 = (float4*)xs;
        for (int i = tid; i < GNM * 32; i += 256) {
            int row = i >> 5, kg = i & 31;  // coalesced: 512B contiguous per row
            int ne = node0 + row;
            if (ne >= NN) ne = NN - 1;      // clamp: dup read, store predicated
            xs4[row * 32 + (kg ^ (row & 7))] = X4[ne * 32 + kg];
        }
    }
    __syncthreads();

    const int wave = tid >> 6, lane = tid & 63;
    const int la = lane >> 4, ln = lane & 15;
    const int lx = ln & 7;                // (wave*16+ln)&7 == ln&7
    const float* xrow = &xs[(wave * 16 + ln) * 128];
    const v8s* Wf = (const v8s*)Wpk;

    v4f acc[8];
#pragma unroll
    for (int nt = 0; nt < 8; ++nt) acc[nt] = (v4f){0.f, 0.f, 0.f, 0.f};

    for (int kt = 0; kt < 4; ++kt) {
        float4 xa0 = *(const float4*)&xrow[((kt * 8 + la) ^ lx) << 2];
        float4 xa1 = *(const float4*)&xrow[((kt * 8 + la + 4) ^ lx) << 2];
        float xv[8] = {xa0.x, xa0.y, xa0.z, xa0.w, xa1.x, xa1.y, xa1.z, xa1.w};
        v8s ah, al;
#pragma unroll
        for (int j = 0; j < 8; ++j) {
            unsigned short h = f2bf(xv[j]);
            ah[j] = (short)h;
            al[j] = (short)f2bf(xv[j] - bf2f(h));
        }
        const int wbase = (kt * 4 + la) * 8 * 16;
#pragma unroll
        for (int nt = 0; nt < 8; ++nt) {
            v8s bh = Wf[wbase + nt * 16 + ln];
            acc[nt] = __builtin_amdgcn_mfma_f32_16x16x32_bf16(ah, bh, acc[nt], 0, 0, 0);
            acc[nt] = __builtin_amdgcn_mfma_f32_16x16x32_bf16(al, bh, acc[nt], 0, 0, 0);
        }
    }

    // C/D: row = la*4 + r (node), col = ln. Y[node][128] bf16.
#pragma unroll
    for (int r = 0; r < 4; ++r) {
        int node = node0 + wave * 16 + la * 4 + r;
        if (node < NN) {
            float di = dinv[node];
#pragma unroll
            for (int nt = 0; nt < 8; ++nt)
                Y[node * 128 + nt * 16 + ln] = f2bf(acc[nt][r] * di);
        }
    }
}

// ------ fused gather2 + gemm_out (R17): 512 threads, 8 waves -----------------
// R15/R16 lesson: hipcc will NOT materialize two concurrent load chains per
// wave (VGPR pinned at 44 both rounds). Get parallelism from WAVES instead:
// 8 waves x 8 nodes each (same serial 16-deep body the compiler schedules
// well), LDS still 32KB -> 4 blocks/CU x 8 = 32 waves/CU (vs ~10 measured at
// 256 threads). Phase 2 splits MFMA across all 8 waves: wv=wave&3 row-group,
// nh=wave>>2 nt-half -> 4 nt-tiles/wave. Math untouched -> bit-identical.

__launch_bounds__(512, 8)
__global__ void k_gg_out(const uint_t* __restrict__ src, const int* __restrict__ cnt,
                         const uint_t* __restrict__ slots, const float* __restrict__ dinv,
                         const unsigned short* __restrict__ Wpk,
                         const float* __restrict__ bmu, const float* __restrict__ blv,
                         float* __restrict__ out) {
    __shared__ float xs[GNM * 128];     // 32 KB, f4-index XOR-swizzled
    const int tid = threadIdx.x;
    const int node0 = blockIdx.x * GNM;
    const int wave = tid >> 6, lane = tid & 63;

    // phase 1: each of 8 waves aggregates 8 nodes' g-rows into LDS (fp32)
    for (int n = 0; n < 8; ++n) {
        int node = node0 + wave * 8 + n;
        float accx = 0.0f, accy = 0.0f;
        if (node < NN) {
            float di = dinv[node];
            uint_t u = src[node * 64 + lane];
            accx = bf_lo(u);
            accy = bf_hi(u);
            int end = __builtin_amdgcn_readfirstlane(cnt[node]);
            const uint_t* seg = slots + node * CAP;
            for (int jj = 0; jj < end; jj += 16) {
                uint_t rp[16];
#pragma unroll
                for (int q = 0; q < 16; ++q) rp[q] = seg[jj + q];
                uint_t sv[16];
#pragma unroll
                for (int q = 0; q < 16; ++q) sv[q] = src[(rp[q] >> 15) * 64 + lane];
#pragma unroll
                for (int q = 0; q < 16; ++q) {
                    float p = (float)(rp[q] & 0x7fffu) * EW_INV;  // padded: p == 0
                    accx = fmaf(p, bf_lo(sv[q]), accx);
                    accy = fmaf(p, bf_hi(sv[q]), accy);
                }
            }
            accx *= di;
            accy *= di;
        }
        int r = wave * 8 + n;
        int f4 = (lane >> 1) ^ (r & 7);   // (r&7) == (n&7) here too
        *(float2*)&xs[r * 128 + (f4 << 2) + ((lane & 1) << 1)] =
            make_float2(accx, accy);
    }
    __syncthreads();

    // phase 2: MFMA split across 8 waves: wv = row-group, nh = nt-half
    const int wv = wave & 3, nh = wave >> 2;
    const int la = lane >> 4, ln = lane & 15;
    const int lx = ln & 7;
    const float* xrow = &xs[(wv * 16 + ln) * 128];
    const v8s* Wf = (const v8s*)Wpk;

    v4f acc[4];
#pragma unroll
    for (int t = 0; t < 4; ++t) acc[t] = (v4f){0.f, 0.f, 0.f, 0.f};

    for (int kt = 0; kt < 4; ++kt) {
        float4 xa0 = *(const float4*)&xrow[((kt * 8 + la) ^ lx) << 2];
        float4 xa1 = *(const float4*)&xrow[((kt * 8 + la + 4) ^ lx) << 2];
        float xv[8] = {xa0.x, xa0.y, xa0.z, xa0.w, xa1.x, xa1.y, xa1.z, xa1.w};
        v8s ah, al;
#pragma unroll
        for (int j = 0; j < 8; ++j) {
            unsigned short h = f2bf(xv[j]);
            ah[j] = (short)h;
            al[j] = (short)f2bf(xv[j] - bf2f(h));
        }
        const int wbase = (kt * 4 + la) * 8 * 16;
#pragma unroll
        for (int t = 0; t < 4; ++t) {
            int nt = nh * 4 + t;
            v8s bh = Wf[wbase + nt * 16 + ln];
            acc[t] = __builtin_amdgcn_mfma_f32_16x16x32_bf16(ah, bh, acc[t], 0, 0, 0);
            acc[t] = __builtin_amdgcn_mfma_f32_16x16x32_bf16(al, bh, acc[t], 0, 0, 0);
        }
    }

    float bb[4];
#pragma unroll
    for (int t = 0; t < 4; ++t)
        bb[t] = (nh == 0) ? bmu[t * 16 + ln] : blv[t * 16 + ln];

#pragma unroll
    for (int r = 0; r < 4; ++r) {
        int node = node0 + wv * 16 + la * 4 + r;
        if (node < NN) {
#pragma unroll
            for (int t = 0; t < 4; ++t) {
                float v = acc[t][r] + bb[t];
                if (nh == 0)
                    out[node * 64 + t * 16 + ln] = v;
                else
                    out[OUT_HALF + node * 64 + t * 16 + ln] = v;
            }
        }
    }
}

// ---------------- launch ----------------

extern "C" void kernel_launch(void* const* d_in, const int* in_sizes, int n_in,
                              void* d_out, int out_size, void* d_ws, size_t ws_size,
                              hipStream_t stream) {
    const float* x   = (const float*)d_in[0];
    const int*   ei  = (const int*)d_in[1];   // [2, NE] int32 on device
    const float* ew  = (const float*)d_in[2];
    const float* W1  = (const float*)d_in[3];
    const float* b1  = (const float*)d_in[4];
    const float* Wmu = (const float*)d_in[5];
    const float* bmu = (const float*)d_in[6];
    const float* Wlv = (const float*)d_in[7];
    const float* blv = (const float*)d_in[8];
    const int* rowi = ei;        // sources
    const int* coli = ei + NE;   // destinations
    float* out = (float*)d_out;

    // workspace layout (4B elements). Liveness plan:
    //   prep:      Wpk1 -> hole at poolA+NN*64, Wpk2 -> hole+8K floats;
    //              bcnt zeroed. Hole [NN*64..NN*128) is NEVER aliased: bins
    //              overlay ends at 4.3M ints < NN*64 = 6.4M; y0=[0..NN*64);
    //              y1=[NN*128..NN*192). Both Wpk's live to the end.
    //   build:     bins+bcnt overlay poolA[0..4.3M)    (dead after scatter)
    //   gemm_h0:   y0 = poolA[0..NN*64) uints (bf16 [node][128])
    //   gather1:   y1 = poolA[NN*128..NN*192) uints  (y0 dead after)
    //   gg_out:    reads y1 + Wpk2, writes d_out directly
    int*    cnt   = (int*)d_ws;                  // NN ints, pad 100352
    float*  dinv  = (float*)(cnt + 100352);      // NN floats, pad 100352
    uint_t* slots = (uint_t*)(dinv + 100352);    // NN*CAP uints (25.6 MB)
    float*  poolA = (float*)(slots + NN * CAP);  // NN*128 floats (51.2 MB)
    uint_t* y0    = (uint_t*)poolA;              // [NN][64] uints (bf16x2)
    uint_t* y1    = (uint_t*)(poolA + NN * DD);  // [NN][64] uints
    uint2*  bins  = (uint2*)poolA;               // NB*BCAP uint2 (16.8 MB)
    int*    bcnt  = (int*)(poolA + NB * BCAP * 2);   // NB*BSTRIDE ints (64 KB)
    unsigned short* Wpk1 = (unsigned short*)(poolA + NN * 64);         // 32 KB
    unsigned short* Wpk2 = (unsigned short*)(poolA + NN * 64 + 8192);  // 32 KB

    const int B = 256;
    const int GGRID = (NN + GNM - 1) / GNM;  // 1563
    // one prep launch: pack W1 -> Wpk1, [Wmu|Wlv] -> Wpk2, zero bcnt
    k_prep<<<80, B, 0, stream>>>(W1, Wmu, Wlv, Wpk1, Wpk2, bcnt);
    k_bin<<<(NE + CHUNK - 1) / CHUNK, B, 0, stream>>>(rowi, coli, ew, bcnt, bins);
    k_scatter<<<NB, 512, 0, stream>>>(bcnt, bins, cnt, slots, dinv);
    // layer 1 (MFMA): y0 = dinv .* (x @ W1) -> bf16 [node][128]
    k_gemm_h0<<<GGRID, B, 0, stream>>>(x, Wpk1, dinv, (unsigned short*)y0);
    // y1 = dinv .* relu(dinv .* (y0[c] + sum ew*y0[r]) + b1) -> bf16
    k_gather<true, true><<<(NN * 64 + B - 1) / B, B, 0, stream>>>(
        y0, cnt, slots, dinv, b1, y1);
    // fused: aggregate y1 -> LDS -> MFMA -> [mu|logvar] (512 thr, 8 waves)
    k_gg_out<<<GGRID, 512, 0, stream>>>(y1, cnt, slots, dinv, Wpk2, bmu, blv, out);
}